// Round 9
// baseline (25858.093 us; speedup 1.0000x reference)
//
#include <hip/hip_runtime.h>

// Problem constants
constexpr int nB = 32, nT = 4096, nK = 256, nTP = 1024;

__device__ __forceinline__ float sigmoidf_(float x) { return 1.f / (1.f + expf(-x)); }

typedef unsigned int u32x4 __attribute__((ext_vector_type(4)));

// write-through stores: sc0 sc1 -> visible at device coherence point (memory-side)
__device__ __forceinline__ void store_u32_wt(unsigned* p, unsigned v) {
  asm volatile("global_store_dword %0, %1, off sc0 sc1" :: "v"(p), "v"(v) : "memory");
}
__device__ __forceinline__ void store_f32_wt(float* p, float v) {
  asm volatile("global_store_dword %0, %1, off sc0 sc1" :: "v"(p), "v"(v) : "memory");
}

// cross-lane helpers: bit-identical replacements for __shfl_xor(x, m, 32)
__device__ __forceinline__ float dpp_xor1(float x) {
  return __int_as_float(__builtin_amdgcn_update_dpp(0, __float_as_int(x), 0xB1, 0xF, 0xF, true));
}
__device__ __forceinline__ float dpp_xor2(float x) {
  return __int_as_float(__builtin_amdgcn_update_dpp(0, __float_as_int(x), 0x4E, 0xF, 0xF, true));
}
__device__ __forceinline__ float dpp_xor8(float x) {
  return __int_as_float(__builtin_amdgcn_update_dpp(0, __float_as_int(x), 0x128, 0xF, 0xF, true));
}
__device__ __forceinline__ float swz_xor4(float x) {
  return __int_as_float(__builtin_amdgcn_ds_swizzle(__float_as_int(x), 0x101F));
}
__device__ __forceinline__ float swz_xor16(float x) {
  return __int_as_float(__builtin_amdgcn_ds_swizzle(__float_as_int(x), 0x401F));
}

// ---------------- tokenizer (unchanged, verified absmax 0) ----------------

__global__ __launch_bounds__(256) void k_mean(const float* __restrict__ x, float* __restrict__ sig) {
  int row = blockIdx.x * 4 + (threadIdx.x >> 6);
  int lane = threadIdx.x & 63;
  float v = x[(size_t)row * 64 + lane];
  #pragma unroll
  for (int off = 32; off > 0; off >>= 1) v += __shfl_down(v, off, 64);
  if (lane == 0) sig[row] = v * (1.0f / 64.0f);
}

__global__ __launch_bounds__(256) void k_conv1(const float* __restrict__ sig,
    const float* __restrict__ w1, const float* __restrict__ b1, float* __restrict__ h1) {
  int idx = blockIdx.x * 256 + threadIdx.x;
  int o = idx & 2047;
  int co = (idx >> 11) & 63;
  int b = idx >> 17;
  const float* s = sig + (size_t)b * nT;
  float acc = b1[co];
  int base = 2 * o - 1;
  #pragma unroll
  for (int j = 0; j < 4; j++) {
    int p = base + j;
    float sv = (p >= 0 && p < nT) ? s[p] : 0.f;
    acc = fmaf(w1[co * 4 + j], sv, acc);
  }
  h1[idx] = fmaxf(acc, 0.f);
}

__global__ __launch_bounds__(256) void k_conv2(const float* __restrict__ h1,
    const float* __restrict__ w2, const float* __restrict__ b2, float* __restrict__ h2) {
  int blk = blockIdx.x;
  int otile = blk & 3, co = (blk >> 2) & 63, b = blk >> 8;
  int o = otile * 256 + threadIdx.x;
  __shared__ float w[256];
  w[threadIdx.x] = w2[co * 256 + threadIdx.x];
  __syncthreads();
  const float* hin = h1 + (size_t)b * 64 * 2048;
  float acc = b2[co];
  int base = 2 * o - 1;
  for (int ci = 0; ci < 64; ci++) {
    const float* r = hin + ci * 2048;
    const float* wc = w + ci * 4;
    #pragma unroll
    for (int j = 0; j < 4; j++) {
      int p = base + j;
      float v = (p >= 0 && p < 2048) ? r[p] : 0.f;
      acc = fmaf(wc[j], v, acc);
    }
  }
  h2[((size_t)b * 64 + co) * 1024 + o] = fmaxf(acc, 0.f);
}

__global__ __launch_bounds__(256) void k_conv3(const float* __restrict__ h2,
    const float* __restrict__ w3, const float* __restrict__ b3, float* __restrict__ ze) {
  int blk = blockIdx.x;
  int otile = blk & 3, co = (blk >> 2) & 63, b = blk >> 8;
  int o = otile * 256 + threadIdx.x;
  __shared__ float w[192];
  if (threadIdx.x < 192) w[threadIdx.x] = w3[co * 192 + threadIdx.x];
  __syncthreads();
  const float* hin = h2 + (size_t)b * 64 * 1024;
  float acc = b3[co];
  for (int ci = 0; ci < 64; ci++) {
    const float* r = hin + ci * 1024;
    const float* wc = w + ci * 3;
    #pragma unroll
    for (int j = 0; j < 3; j++) {
      int p = o - 1 + j;
      float v = (p >= 0 && p < 1024) ? r[p] : 0.f;
      acc = fmaf(wc[j], v, acc);
    }
  }
  ze[((size_t)b * 64 + co) * 1024 + o] = acc;
}

__global__ __launch_bounds__(256) void k_cbnorm(const float* __restrict__ cb, float* __restrict__ cbn) {
  int k = threadIdx.x;
  const float4* c4 = (const float4*)(cb + (size_t)k * 64);
  float acc = 0.f;
  #pragma unroll
  for (int q = 0; q < 16; q++) {
    float4 e = c4[q];
    acc = fmaf(e.x, e.x, fmaf(e.y, e.y, fmaf(e.z, e.z, fmaf(e.w, e.w, acc))));
  }
  cbn[k] = acc;
}

__global__ __launch_bounds__(256) void k_vq(const float* __restrict__ ze,
    const float* __restrict__ cb, const float* __restrict__ cbn, float* __restrict__ zq) {
  __shared__ float scb[nK * 64];
  for (int i = threadIdx.x; i < nK * 64; i += 256) scb[i] = cb[i];
  __syncthreads();
  int g = blockIdx.x * 256 + threadIdx.x;
  int b = g >> 10, o = g & 1023;
  const float* zb = ze + (size_t)b * 64 * 1024 + o;
  float z[64];
  #pragma unroll
  for (int d = 0; d < 64; d++) z[d] = zb[(size_t)d * 1024];
  float best = 3.4e38f; int bi = 0;
  for (int k = 0; k < nK; k++) {
    const float4* ck = (const float4*)(scb + k * 64);
    float dot = 0.f;
    #pragma unroll
    for (int q = 0; q < 16; q++) {
      float4 c4 = ck[q];
      dot = fmaf(c4.x, z[4 * q + 0], dot);
      dot = fmaf(c4.y, z[4 * q + 1], dot);
      dot = fmaf(c4.z, z[4 * q + 2], dot);
      dot = fmaf(c4.w, z[4 * q + 3], dot);
    }
    float s = cbn[k] - 2.f * dot;
    if (s < best) { best = s; bi = k; }
  }
  float4* zo4 = (float4*)(zq + (size_t)g * 64);
  const float4* cbest = (const float4*)(scb + bi * 64);
  #pragma unroll
  for (int q = 0; q < 16; q++) zo4[q] = cbest[q];
}

// transpose zq [b][t][d] -> zqT [t][d][b]
__global__ __launch_bounds__(256) void k_zqt(const float* __restrict__ zq, float* __restrict__ zqT) {
  int t = blockIdx.x;
  for (int o = threadIdx.x; o < 2048; o += 256) {
    int d = o >> 5, b = o & 31;
    zqT[(size_t)t * 2048 + o] = zq[((size_t)b * nTP + t) * 64 + d];
  }
}

// ---------------- persistent fused 2-layer LSTM + head ----------------
// Round-15: L0/L1 WAVE SPECIALIZATION. r14 (16.5ms) validated the LDS/stall
// axis; remaining serial chain per wave = stage -> L0 -> vbuf(MALL) -> L1.
// Split the 8 waves: team0 (waves 0-3) = L0 only, 8 batches/group (r11's
// verified 8-batch FMA block); team1 (waves 4-7) = L1 only, BOTH dims per
// group sharing one vbuf[32] (128 VGPR), with c<16 global h1 loads issued at
// iteration TOP (hidden under staging + team0 compute). Per-wave serial work
// halves; teams mutually hide stalls. All per-acc FMA sequences, butterfly
// tree (1,2,4,8,16), gate order bit-identical -> absmax 0.0.
// launch_bounds(512,1): lifts the 128-VGPR remat trap (r13); occupancy is
// LDS-bound at 1 block/CU anyway (~119KB LDS).

__global__ __launch_bounds__(512, 1) void k_lstm(
    const float* __restrict__ zqT,
    const float* __restrict__ wih0, const float* __restrict__ whh0, const float* __restrict__ bl0,
    const float* __restrict__ wih1, const float* __restrict__ whh1, const float* __restrict__ bl1,
    const float* __restrict__ wout, const float* __restrict__ bout,
    float* __restrict__ st, float* __restrict__ out)
{
  __shared__ float wB [2][4][32][36];
  __shared__ float wAh[2][4][32][20];
  __shared__ float wAz[2][4][64];
  __shared__ float wHd[2][512];
  __shared__ float bHd[2];
  __shared__ float h0s[16384];   // staged h0[t-1], XOR-swizzled [512][32]

  float* h0T = st;                          // [2][512][32]
  float* h1T = st + 32768;                  // [2][512][32]
  unsigned* flags = (unsigned*)(st + 65536); // [256]

  const int blk  = blockIdx.x;
  const int tid  = threadIdx.x;
  const int team = tid >> 8;                // 0: L0 waves, 1: L1 waves
  const int grp  = (tid >> 5) & 7;
  const int c    = tid & 31;
  const int dimA = grp & 1;                 // team0: row j = 2*blk + dimA
  const int b0A  = (grp >> 1) * 8;          // team0: 8 batches
  const int b0B  = grp * 4;                 // team1: 4 batches, both dims
  const int jA   = 2 * blk + dimA;

  // ---- stage weights into LDS ----
  for (int idx = tid; idx < 2 * 4 * 32 * 32; idx += 512) {
    int k = idx & 31, cc = (idx >> 5) & 31, gg = (idx >> 10) & 3, dd = idx >> 12;
    int row = gg * 512 + 2 * blk + dd;
    float v = (cc < 16) ? whh1[(size_t)row * 512 + cc * 32 + k]
                        : wih1[(size_t)row * 512 + (cc - 16) * 32 + k];
    wB[dd][gg][cc][k] = v;
  }
  for (int idx = tid; idx < 2 * 4 * 32 * 16; idx += 512) {
    int k = idx & 15, cc = (idx >> 4) & 31, gg = (idx >> 9) & 3, dd = idx >> 11;
    wAh[dd][gg][cc][k] = whh0[(size_t)(gg * 512 + 2 * blk + dd) * 512 + cc * 16 + k];
  }
  if (tid < 512) {
    int d = tid & 63, gg = (tid >> 6) & 3, dd = tid >> 8;
    wAz[dd][gg][d] = wih0[(size_t)(gg * 512 + 2 * blk + dd) * 64 + d];
  }
  if (blk < 96) {
    for (int idx = tid; idx < 1024; idx += 512) {
      int q = idx >> 9, i = idx & 511;
      int p = blk * 2 + q;
      wHd[q][i] = wout[(size_t)(p >> 5) * 512 + i];
      if (i == 0) bHd[q] = bout[p >> 5];
    }
  }
  float bA[4], bB4d[2][4];
  #pragma unroll
  for (int g = 0; g < 4; g++) {
    bA[g] = bl0[g * 512 + jA];
    #pragma unroll
    for (int dd = 0; dd < 2; dd++) bB4d[dd][g] = bl1[g * 512 + 2 * blk + dd];
  }
  float creg0 = 0.f;            // team0 lanes c<8: cell (jA, b0A+c)
  float creg1[2] = {0.f, 0.f};  // team1 lanes c<4: cell (2blk+dd, b0B+c)
  __syncthreads();

  // per-lane swizzled LDS base pointers (swizzle bits 2-4)
  const float* p0a = h0s + ((c * 512 + b0A) ^ ((c & 7) << 2));       // L0 rows c*16+i, cols b0A..+3
  const float* p0b = h0s + ((c * 512 + b0A + 4) ^ ((c & 7) << 2));   // cols b0A+4..+7
  const int cp = (c < 16) ? 0 : (c - 16);
  const float* pA = h0s + ((cp * 1024 + b0B) ^ (((2 * cp) & 7) << 2));        // L1 rows cp*32+k, k<16
  const float* pB = h0s + ((cp * 1024 + 512 + b0B) ^ (((2 * cp + 1) & 7) << 2)); // k>=16

  for (int t = 0; t <= nTP + 1; t++) {
    // ---- team1: issue global h1[t-2] loads NOW (hidden under stage + L0) ----
    float4 vbuf[32];
    if (team == 1 && t >= 1 && t <= nTP && c < 16) {
      const float* vg = h1T + ((t - 1) & 1) * 16384 + c * 32 * 32 + b0B;
      #pragma unroll
      for (int k = 0; k < 32; k++) vbuf[k] = *(const float4*)(vg + k * 32);
    }
    // ---- team0: prefetch zqT input for step t ----
    float4 u0a, u0b, u1a, u1b;
    if (team == 0 && t < nTP) {
      const float* zt = zqT + (size_t)t * 2048 + b0A;
      u0a = *(const float4*)(zt + (c * 2 + 0) * 32);
      u0b = *(const float4*)(zt + (c * 2 + 0) * 32 + 4);
      u1a = *(const float4*)(zt + (c * 2 + 1) * 32);
      u1b = *(const float4*)(zt + (c * 2 + 1) * 32 + 4);
    }

    // ---- stage h0[t-1] (global, post-barrier-fresh) into swizzled LDS ----
    if (t <= nTP) {
      const float* src = h0T + (t & 1) * 16384;
      #pragma unroll
      for (int q = 0; q < 8; q++) {
        int lin = (q * 512 + tid) * 4;
        float4 v = *(const float4*)(src + lin);
        int phys = lin ^ (((lin >> 9) & 7) << 2);
        *(float4*)&h0s[phys] = v;
      }
      __syncthreads();
    }

    // ---- team0: L0 step t (8 batches, r11-verified block) ----
    if (team == 0 && t < nTP) {
      float acc[32];
      #pragma unroll
      for (int r = 0; r < 32; r++) acc[r] = 0.f;
      #pragma unroll
      for (int s = 0; s < 4; s++) {
        float4 v0a = *(const float4*)(p0a + (s * 4 + 0) * 32);
        float4 v0b = *(const float4*)(p0b + (s * 4 + 0) * 32);
        float4 v1a = *(const float4*)(p0a + (s * 4 + 1) * 32);
        float4 v1b = *(const float4*)(p0b + (s * 4 + 1) * 32);
        float4 v2a = *(const float4*)(p0a + (s * 4 + 2) * 32);
        float4 v2b = *(const float4*)(p0b + (s * 4 + 2) * 32);
        float4 v3a = *(const float4*)(p0a + (s * 4 + 3) * 32);
        float4 v3b = *(const float4*)(p0b + (s * 4 + 3) * 32);
        #pragma unroll
        for (int g = 0; g < 4; g++) {
          float4 w = *(const float4*)&wAh[dimA][g][c][s * 4];
          float* a = acc + g * 8;
          a[0]=fmaf(w.x,v0a.x,a[0]); a[0]=fmaf(w.y,v1a.x,a[0]); a[0]=fmaf(w.z,v2a.x,a[0]); a[0]=fmaf(w.w,v3a.x,a[0]);
          a[1]=fmaf(w.x,v0a.y,a[1]); a[1]=fmaf(w.y,v1a.y,a[1]); a[1]=fmaf(w.z,v2a.y,a[1]); a[1]=fmaf(w.w,v3a.y,a[1]);
          a[2]=fmaf(w.x,v0a.z,a[2]); a[2]=fmaf(w.y,v1a.z,a[2]); a[2]=fmaf(w.z,v2a.z,a[2]); a[2]=fmaf(w.w,v3a.z,a[2]);
          a[3]=fmaf(w.x,v0a.w,a[3]); a[3]=fmaf(w.y,v1a.w,a[3]); a[3]=fmaf(w.z,v2a.w,a[3]); a[3]=fmaf(w.w,v3a.w,a[3]);
          a[4]=fmaf(w.x,v0b.x,a[4]); a[4]=fmaf(w.y,v1b.x,a[4]); a[4]=fmaf(w.z,v2b.x,a[4]); a[4]=fmaf(w.w,v3b.x,a[4]);
          a[5]=fmaf(w.x,v0b.y,a[5]); a[5]=fmaf(w.y,v1b.y,a[5]); a[5]=fmaf(w.z,v2b.y,a[5]); a[5]=fmaf(w.w,v3b.y,a[5]);
          a[6]=fmaf(w.x,v0b.z,a[6]); a[6]=fmaf(w.y,v1b.z,a[6]); a[6]=fmaf(w.z,v2b.z,a[6]); a[6]=fmaf(w.w,v3b.z,a[6]);
          a[7]=fmaf(w.x,v0b.w,a[7]); a[7]=fmaf(w.y,v1b.w,a[7]); a[7]=fmaf(w.z,v2b.w,a[7]); a[7]=fmaf(w.w,v3b.w,a[7]);
        }
      }
      {
        #pragma unroll
        for (int g = 0; g < 4; g++) {
          float wx = wAz[dimA][g][c * 2 + 0], wy = wAz[dimA][g][c * 2 + 1];
          float* a = acc + g * 8;
          a[0]=fmaf(wx,u0a.x,a[0]); a[0]=fmaf(wy,u1a.x,a[0]);
          a[1]=fmaf(wx,u0a.y,a[1]); a[1]=fmaf(wy,u1a.y,a[1]);
          a[2]=fmaf(wx,u0a.z,a[2]); a[2]=fmaf(wy,u1a.z,a[2]);
          a[3]=fmaf(wx,u0a.w,a[3]); a[3]=fmaf(wy,u1a.w,a[3]);
          a[4]=fmaf(wx,u0b.x,a[4]); a[4]=fmaf(wy,u1b.x,a[4]);
          a[5]=fmaf(wx,u0b.y,a[5]); a[5]=fmaf(wy,u1b.y,a[5]);
          a[6]=fmaf(wx,u0b.z,a[6]); a[6]=fmaf(wy,u1b.z,a[6]);
          a[7]=fmaf(wx,u0b.w,a[7]); a[7]=fmaf(wy,u1b.w,a[7]);
        }
      }
      #pragma unroll
      for (int r = 0; r < 32; r++) acc[r] += dpp_xor1(acc[r]);
      #pragma unroll
      for (int r = 0; r < 32; r++) acc[r] += dpp_xor2(acc[r]);
      #pragma unroll
      for (int r = 0; r < 32; r++) acc[r] += swz_xor4(acc[r]);
      #pragma unroll
      for (int r = 0; r < 32; r++) acc[r] += dpp_xor8(acc[r]);
      #pragma unroll
      for (int r = 0; r < 32; r++) acc[r] += swz_xor16(acc[r]);
      if (c < 8) {
        int b = b0A + c;
        float gi = sigmoidf_(acc[0 * 8 + c] + bA[0]);
        float gf = sigmoidf_(acc[1 * 8 + c] + bA[1]);
        float gg = tanhf    (acc[2 * 8 + c] + bA[2]);
        float go = sigmoidf_(acc[3 * 8 + c] + bA[3]);
        float cn = fmaf(gf, creg0, gi * gg);
        creg0 = cn;
        store_f32_wt(h0T + ((t + 1) & 1) * 16384 + jA * 32 + b, go * tanhf(cn));
      }
    }

    // ---- team1: L1 step t-1 (both dims, shared vbuf) ----
    if (team == 1 && t >= 1 && t <= nTP) {
      if (c >= 16) {
        #pragma unroll
        for (int k = 0; k < 16; k++) vbuf[k] = *(const float4*)(pA + k * 32);
        #pragma unroll
        for (int k = 0; k < 16; k++) vbuf[16 + k] = *(const float4*)(pB + k * 32);
      }
      float acc[32];   // [dd][g][bi] = dd*16 + g*4 + bi
      #pragma unroll
      for (int r = 0; r < 32; r++) acc[r] = 0.f;
      #pragma unroll
      for (int s = 0; s < 8; s++) {
        float4 v0 = vbuf[s * 4 + 0];
        float4 v1 = vbuf[s * 4 + 1];
        float4 v2 = vbuf[s * 4 + 2];
        float4 v3 = vbuf[s * 4 + 3];
        #pragma unroll
        for (int dd = 0; dd < 2; dd++) {
          #pragma unroll
          for (int g = 0; g < 4; g++) {
            float4 w = *(const float4*)&wB[dd][g][c][s * 4];
            float* a = acc + dd * 16 + g * 4;
            a[0]=fmaf(w.x,v0.x,a[0]); a[0]=fmaf(w.y,v1.x,a[0]); a[0]=fmaf(w.z,v2.x,a[0]); a[0]=fmaf(w.w,v3.x,a[0]);
            a[1]=fmaf(w.x,v0.y,a[1]); a[1]=fmaf(w.y,v1.y,a[1]); a[1]=fmaf(w.z,v2.y,a[1]); a[1]=fmaf(w.w,v3.y,a[1]);
            a[2]=fmaf(w.x,v0.z,a[2]); a[2]=fmaf(w.y,v1.z,a[2]); a[2]=fmaf(w.z,v2.z,a[2]); a[2]=fmaf(w.w,v3.z,a[2]);
            a[3]=fmaf(w.x,v0.w,a[3]); a[3]=fmaf(w.y,v1.w,a[3]); a[3]=fmaf(w.z,v2.w,a[3]); a[3]=fmaf(w.w,v3.w,a[3]);
          }
        }
      }
      #pragma unroll
      for (int r = 0; r < 32; r++) acc[r] += dpp_xor1(acc[r]);
      #pragma unroll
      for (int r = 0; r < 32; r++) acc[r] += dpp_xor2(acc[r]);
      #pragma unroll
      for (int r = 0; r < 32; r++) acc[r] += swz_xor4(acc[r]);
      #pragma unroll
      for (int r = 0; r < 32; r++) acc[r] += dpp_xor8(acc[r]);
      #pragma unroll
      for (int r = 0; r < 32; r++) acc[r] += swz_xor16(acc[r]);
      if (c < 4) {
        int b = b0B + c;
        #pragma unroll
        for (int dd = 0; dd < 2; dd++) {
          float gi = sigmoidf_(acc[dd * 16 + 0 * 4 + c] + bB4d[dd][0]);
          float gf = sigmoidf_(acc[dd * 16 + 1 * 4 + c] + bB4d[dd][1]);
          float gg = tanhf    (acc[dd * 16 + 2 * 4 + c] + bB4d[dd][2]);
          float go = sigmoidf_(acc[dd * 16 + 3 * 4 + c] + bB4d[dd][3]);
          float cn = fmaf(gf, creg1[dd], gi * gg);
          creg1[dd] = cn;
          store_f32_wt(h1T + (t & 1) * 16384 + (2 * blk + dd) * 32 + b, go * tanhf(cn));
        }
      }
    }

    // drain this wave's loads and write-through stores, then block-wide rendezvous
    asm volatile("s_waitcnt vmcnt(0)" ::: "memory");
    __syncthreads();

    // ---- arrival flag (all waves drained at this point) ----
    if (t <= nTP && tid == 0) store_u32_wt(flags + blk, (unsigned)(t + 1));

    // ---- head for step t-2 on wave 1, overlapping the barrier wait ----
    // STANDALONE guard: must also run at t == nTP+1 (emits output step 1023).
    if (t >= 2 && blk < 96 && tid >= 64 && tid < 80) {
      int q = (tid >> 3) & 1, l = tid & 7;
      int p = blk * 2 + q;
      int b = p & 31;
      const float* h1s = h1T + ((t - 1) & 1) * 16384;   // h1 step t-2 (covered by barrier t-1)
      float a = 0.f;
      #pragma unroll 8
      for (int m = 0; m < 64; m++) {
        int i = l * 64 + m;
        a = fmaf(wHd[q][i], h1s[i * 32 + b], a);
      }
      a += __shfl_down(a, 4, 8);
      a += __shfl_down(a, 2, 8);
      a += __shfl_down(a, 1, 8);
      if (l == 0) out[((size_t)b * nTP + (t - 2)) * 6 + (p >> 5)] = a + bHd[q];
    }

    // ---- flat barrier: every block's wave 0 polls all 256 flags ----
    if (t <= nTP) {
      unsigned tgt = (unsigned)(t + 1);
      if (tid < 64) {
        const u32x4* fp = (const u32x4*)flags + tid;
        for (;;) {
          u32x4 f;
          asm volatile("global_load_dwordx4 %0, %1, off sc0 sc1\n\ts_waitcnt vmcnt(0)"
                       : "=&v"(f) : "v"(fp) : "memory");
          bool ok = (f.x >= tgt) && (f.y >= tgt) && (f.z >= tgt) && (f.w >= tgt);
          if (__all(ok)) break;
          __builtin_amdgcn_s_sleep(1);
        }
        __builtin_amdgcn_fence(__ATOMIC_ACQUIRE, "agent");  // buffer_inv
      }
      __syncthreads();
    }
  }
}

// ---------------- launch ----------------

extern "C" void kernel_launch(void* const* d_in, const int* in_sizes, int n_in,
                              void* d_out, int out_size, void* d_ws, size_t ws_size,
                              hipStream_t stream) {
  (void)in_sizes; (void)n_in; (void)out_size; (void)ws_size;
  const float* x    = (const float*)d_in[0];
  const float* w1   = (const float*)d_in[1];
  const float* b1   = (const float*)d_in[2];
  const float* w2   = (const float*)d_in[3];
  const float* b2   = (const float*)d_in[4];
  const float* w3   = (const float*)d_in[5];
  const float* b3   = (const float*)d_in[6];
  const float* cb   = (const float*)d_in[7];
  const float* wih0 = (const float*)d_in[8];
  const float* whh0 = (const float*)d_in[9];
  const float* bl0  = (const float*)d_in[10];
  const float* wih1 = (const float*)d_in[11];
  const float* whh1 = (const float*)d_in[12];
  const float* bl1  = (const float*)d_in[13];
  const float* wout = (const float*)d_in[14];
  const float* bout = (const float*)d_in[15];
  float* out = (float*)d_out;

  float* ws  = (float*)d_ws;
  // region reuse: st+flags overlaps sig (dead after conv1); zqT overlaps h1c (dead after conv2)
  float* sig = ws;                 // 131072 floats (later: h0T/h1T 65536 + flags)
  float* h1c = sig + 131072;       // 4194304  [32][64][2048] (later: zqT, 2097152)
  float* h2c = h1c + 4194304;      // 2097152  [32][64][1024]
  float* ze  = h2c + 2097152;      // 2097152  [32][64][1024]
  float* zq  = ze  + 2097152;      // 2097152  [32*1024][64]
  float* cbn = zq  + 2097152;      // 256
  float* stp = ws;                 // h0T[2][512][32], h1T[2][512][32], flags[256]
  float* zqT = h1c;                // 2097152  [1024][64][32]

  k_mean <<<32768, 256, 0, stream>>>(x, sig);
  k_conv1<<<16384, 256, 0, stream>>>(sig, w1, b1, h1c);
  hipMemsetAsync(stp, 0, (65536 + 1024) * sizeof(float), stream);  // state + flags
  k_conv2<<<8192, 256, 0, stream>>>(h1c, w2, b2, h2c);
  k_conv3<<<8192, 256, 0, stream>>>(h2c, w3, b3, ze);
  k_cbnorm<<<1, 256, 0, stream>>>(cb, cbn);
  k_vq   <<<128, 256, 0, stream>>>(ze, cb, cbn, zq);
  k_zqt  <<<1024, 256, 0, stream>>>(zq, zqT);   // h1c dead now; write zqT over it

  void* kargs[] = { (void*)&zqT, (void*)&wih0, (void*)&whh0, (void*)&bl0,
                    (void*)&wih1, (void*)&whh1, (void*)&bl1,
                    (void*)&wout, (void*)&bout, (void*)&stp, (void*)&out };
  hipLaunchCooperativeKernel((void*)k_lstm, dim3(256), dim3(512), kargs, 0, stream);
}

// Round 10
// 15237.547 us; speedup vs baseline: 1.6970x; 1.6970x over previous
//
#include <hip/hip_runtime.h>

// Problem constants
constexpr int nB = 32, nT = 4096, nK = 256, nTP = 1024;

__device__ __forceinline__ float sigmoidf_(float x) { return 1.f / (1.f + expf(-x)); }

typedef unsigned int u32x4 __attribute__((ext_vector_type(4)));

// write-through stores: sc0 sc1 -> visible at device coherence point (memory-side)
__device__ __forceinline__ void store_u32_wt(unsigned* p, unsigned v) {
  asm volatile("global_store_dword %0, %1, off sc0 sc1" :: "v"(p), "v"(v) : "memory");
}
__device__ __forceinline__ void store_f32_wt(float* p, float v) {
  asm volatile("global_store_dword %0, %1, off sc0 sc1" :: "v"(p), "v"(v) : "memory");
}
__device__ __forceinline__ unsigned load_u32_wt(const unsigned* p) {
  unsigned v;
  asm volatile("global_load_dword %0, %1, off sc0 sc1\n\ts_waitcnt vmcnt(0)"
               : "=&v"(v) : "v"(p) : "memory");
  return v;
}

// cross-lane helpers: bit-identical replacements for __shfl_xor(x, m, 32)
__device__ __forceinline__ float dpp_xor1(float x) {
  return __int_as_float(__builtin_amdgcn_update_dpp(0, __float_as_int(x), 0xB1, 0xF, 0xF, true));
}
__device__ __forceinline__ float dpp_xor2(float x) {
  return __int_as_float(__builtin_amdgcn_update_dpp(0, __float_as_int(x), 0x4E, 0xF, 0xF, true));
}
__device__ __forceinline__ float dpp_xor8(float x) {
  return __int_as_float(__builtin_amdgcn_update_dpp(0, __float_as_int(x), 0x128, 0xF, 0xF, true));
}
__device__ __forceinline__ float swz_xor4(float x) {
  return __int_as_float(__builtin_amdgcn_ds_swizzle(__float_as_int(x), 0x101F));
}
__device__ __forceinline__ float swz_xor16(float x) {
  return __int_as_float(__builtin_amdgcn_ds_swizzle(__float_as_int(x), 0x401F));
}

// ---------------- tokenizer (unchanged, verified absmax 0) ----------------

__global__ __launch_bounds__(256) void k_mean(const float* __restrict__ x, float* __restrict__ sig) {
  int row = blockIdx.x * 4 + (threadIdx.x >> 6);
  int lane = threadIdx.x & 63;
  float v = x[(size_t)row * 64 + lane];
  #pragma unroll
  for (int off = 32; off > 0; off >>= 1) v += __shfl_down(v, off, 64);
  if (lane == 0) sig[row] = v * (1.0f / 64.0f);
}

__global__ __launch_bounds__(256) void k_conv1(const float* __restrict__ sig,
    const float* __restrict__ w1, const float* __restrict__ b1, float* __restrict__ h1) {
  int idx = blockIdx.x * 256 + threadIdx.x;
  int o = idx & 2047;
  int co = (idx >> 11) & 63;
  int b = idx >> 17;
  const float* s = sig + (size_t)b * nT;
  float acc = b1[co];
  int base = 2 * o - 1;
  #pragma unroll
  for (int j = 0; j < 4; j++) {
    int p = base + j;
    float sv = (p >= 0 && p < nT) ? s[p] : 0.f;
    acc = fmaf(w1[co * 4 + j], sv, acc);
  }
  h1[idx] = fmaxf(acc, 0.f);
}

__global__ __launch_bounds__(256) void k_conv2(const float* __restrict__ h1,
    const float* __restrict__ w2, const float* __restrict__ b2, float* __restrict__ h2) {
  int blk = blockIdx.x;
  int otile = blk & 3, co = (blk >> 2) & 63, b = blk >> 8;
  int o = otile * 256 + threadIdx.x;
  __shared__ float w[256];
  w[threadIdx.x] = w2[co * 256 + threadIdx.x];
  __syncthreads();
  const float* hin = h1 + (size_t)b * 64 * 2048;
  float acc = b2[co];
  int base = 2 * o - 1;
  for (int ci = 0; ci < 64; ci++) {
    const float* r = hin + ci * 2048;
    const float* wc = w + ci * 4;
    #pragma unroll
    for (int j = 0; j < 4; j++) {
      int p = base + j;
      float v = (p >= 0 && p < 2048) ? r[p] : 0.f;
      acc = fmaf(wc[j], v, acc);
    }
  }
  h2[((size_t)b * 64 + co) * 1024 + o] = fmaxf(acc, 0.f);
}

__global__ __launch_bounds__(256) void k_conv3(const float* __restrict__ h2,
    const float* __restrict__ w3, const float* __restrict__ b3, float* __restrict__ ze) {
  int blk = blockIdx.x;
  int otile = blk & 3, co = (blk >> 2) & 63, b = blk >> 8;
  int o = otile * 256 + threadIdx.x;
  __shared__ float w[192];
  if (threadIdx.x < 192) w[threadIdx.x] = w3[co * 192 + threadIdx.x];
  __syncthreads();
  const float* hin = h2 + (size_t)b * 64 * 1024;
  float acc = b3[co];
  for (int ci = 0; ci < 64; ci++) {
    const float* r = hin + ci * 1024;
    const float* wc = w + ci * 3;
    #pragma unroll
    for (int j = 0; j < 3; j++) {
      int p = o - 1 + j;
      float v = (p >= 0 && p < 1024) ? r[p] : 0.f;
      acc = fmaf(wc[j], v, acc);
    }
  }
  ze[((size_t)b * 64 + co) * 1024 + o] = acc;
}

__global__ __launch_bounds__(256) void k_cbnorm(const float* __restrict__ cb, float* __restrict__ cbn) {
  int k = threadIdx.x;
  const float4* c4 = (const float4*)(cb + (size_t)k * 64);
  float acc = 0.f;
  #pragma unroll
  for (int q = 0; q < 16; q++) {
    float4 e = c4[q];
    acc = fmaf(e.x, e.x, fmaf(e.y, e.y, fmaf(e.z, e.z, fmaf(e.w, e.w, acc))));
  }
  cbn[k] = acc;
}

__global__ __launch_bounds__(256) void k_vq(const float* __restrict__ ze,
    const float* __restrict__ cb, const float* __restrict__ cbn, float* __restrict__ zq) {
  __shared__ float scb[nK * 64];
  for (int i = threadIdx.x; i < nK * 64; i += 256) scb[i] = cb[i];
  __syncthreads();
  int g = blockIdx.x * 256 + threadIdx.x;
  int b = g >> 10, o = g & 1023;
  const float* zb = ze + (size_t)b * 64 * 1024 + o;
  float z[64];
  #pragma unroll
  for (int d = 0; d < 64; d++) z[d] = zb[(size_t)d * 1024];
  float best = 3.4e38f; int bi = 0;
  for (int k = 0; k < nK; k++) {
    const float4* ck = (const float4*)(scb + k * 64);
    float dot = 0.f;
    #pragma unroll
    for (int q = 0; q < 16; q++) {
      float4 c4 = ck[q];
      dot = fmaf(c4.x, z[4 * q + 0], dot);
      dot = fmaf(c4.y, z[4 * q + 1], dot);
      dot = fmaf(c4.z, z[4 * q + 2], dot);
      dot = fmaf(c4.w, z[4 * q + 3], dot);
    }
    float s = cbn[k] - 2.f * dot;
    if (s < best) { best = s; bi = k; }
  }
  float4* zo4 = (float4*)(zq + (size_t)g * 64);
  const float4* cbest = (const float4*)(scb + bi * 64);
  #pragma unroll
  for (int q = 0; q < 16; q++) zo4[q] = cbest[q];
}

// transpose zq [b][t][d] -> zqT [t][d][b]
__global__ __launch_bounds__(256) void k_zqt(const float* __restrict__ zq, float* __restrict__ zqT) {
  int t = blockIdx.x;
  for (int o = threadIdx.x; o < 2048; o += 256) {
    int d = o >> 5, b = o & 31;
    zqT[(size_t)t * 2048 + o] = zq[((size_t)b * nTP + t) * 64 + d];
  }
}

// ---------------- persistent fused 2-layer LSTM + head ----------------
// Round-16: A/B on barrier structure. Compute = r14 byte-identical (16.5ms
// best: h0s LDS staging + XOR swizzle, DPP butterfly, in-phase vbuf).
// LEDGER RE-AUDIT: rounds 0-7 used master/release arrival (only block 0's 64
// lanes poll flags); round 8 introduced the FLAT barrier (16K pollers x 16
// flag lines of uncached sc0sc1 dwordx4 at ~0.3us cadence = saturated MALL
// lines, arrival stores arbitrate into the hammered queue) and r11-r14
// inherited it, confounded with other changes. This round swaps ONLY the
// barrier: master-detect (block 0, 64 pollers) + 256 PRIVATE release lines
// (1 poller each; r7-proven protocol). r9's lesson retained: no register
// arrays live across barriers; r13/r15 lesson: no long-lived reg arrays.

__global__ __launch_bounds__(512, 2) void k_lstm(
    const float* __restrict__ zqT,
    const float* __restrict__ wih0, const float* __restrict__ whh0, const float* __restrict__ bl0,
    const float* __restrict__ wih1, const float* __restrict__ whh1, const float* __restrict__ bl1,
    const float* __restrict__ wout, const float* __restrict__ bout,
    float* __restrict__ st, float* __restrict__ out)
{
  __shared__ float wB [2][4][32][36];
  __shared__ float wAh[2][4][32][20];
  __shared__ float wAz[2][4][64];
  __shared__ float wHd[2][512];
  __shared__ float bHd[2];
  __shared__ float h0s[16384];   // staged h0[t-1], XOR-swizzled [512][32]

  float* h0T = st;                          // [2][512][32]
  float* h1T = st + 32768;                  // [2][512][32]
  unsigned* flags = (unsigned*)(st + 65536); // [256] arrival (16 lines)
  unsigned* rel   = flags + 1024;            // [256*16] one private 64B line per block

  const int blk = blockIdx.x;
  const int tid = threadIdx.x;
  const int dim = tid >> 8;
  const int bg  = (tid >> 5) & 7;
  const int c   = tid & 31;
  const int b0  = bg * 4;
  const int j   = 2 * blk + dim;

  // ---- stage weights into LDS ----
  for (int idx = tid; idx < 2 * 4 * 32 * 32; idx += 512) {
    int k = idx & 31, cc = (idx >> 5) & 31, gg = (idx >> 10) & 3, dd = idx >> 12;
    int row = gg * 512 + 2 * blk + dd;
    float v = (cc < 16) ? whh1[(size_t)row * 512 + cc * 32 + k]
                        : wih1[(size_t)row * 512 + (cc - 16) * 32 + k];
    wB[dd][gg][cc][k] = v;
  }
  for (int idx = tid; idx < 2 * 4 * 32 * 16; idx += 512) {
    int k = idx & 15, cc = (idx >> 4) & 31, gg = (idx >> 9) & 3, dd = idx >> 11;
    wAh[dd][gg][cc][k] = whh0[(size_t)(gg * 512 + 2 * blk + dd) * 512 + cc * 16 + k];
  }
  if (tid < 512) {
    int d = tid & 63, gg = (tid >> 6) & 3, dd = tid >> 8;
    wAz[dd][gg][d] = wih0[(size_t)(gg * 512 + 2 * blk + dd) * 64 + d];
  }
  if (blk < 96) {
    for (int idx = tid; idx < 1024; idx += 512) {
      int q = idx >> 9, i = idx & 511;
      int p = blk * 2 + q;
      wHd[q][i] = wout[(size_t)(p >> 5) * 512 + i];
      if (i == 0) bHd[q] = bout[p >> 5];
    }
  }
  float bA[4], bB4[4];
  #pragma unroll
  for (int g = 0; g < 4; g++) { bA[g] = bl0[g * 512 + j]; bB4[g] = bl1[g * 512 + j]; }
  float creg0 = 0.f, creg1 = 0.f;   // cell state for (j, b0+c), lanes c<4 only
  __syncthreads();

  // per-lane swizzled LDS base pointers (swizzle bits 2-4; offsets use bits >=5)
  const float* h0vL0 = h0s + ((c * 512 + b0) ^ ((c & 7) << 2));
  const int cp = c - 16;
  const float* h0vA = h0s + (((cp < 0 ? 0 : cp) * 1024 + b0) ^ (((2 * (cp < 0 ? 0 : cp)) & 7) << 2));
  const float* h0vB = h0s + (((cp < 0 ? 0 : cp) * 1024 + 512 + b0) ^ (((2 * (cp < 0 ? 0 : cp) + 1) & 7) << 2));

  for (int t = 0; t <= nTP + 1; t++) {
    // ---- stage h0[t-1] (global, post-barrier-fresh) into swizzled LDS ----
    if (t <= nTP) {
      const float* src = h0T + (t & 1) * 16384;
      #pragma unroll
      for (int q = 0; q < 8; q++) {
        int lin = (q * 512 + tid) * 4;
        float4 v = *(const float4*)(src + lin);
        int phys = lin ^ (((lin >> 9) & 7) << 2);
        *(float4*)&h0s[phys] = v;
      }
      __syncthreads();
    }

    // ---- L0 step t (h from LDS) ----
    if (t < nTP) {
      float acc[16];
      #pragma unroll
      for (int r = 0; r < 16; r++) acc[r] = 0.f;
      {
        #pragma unroll
        for (int s = 0; s < 4; s++) {
          float4 v0 = *(const float4*)(h0vL0 + (s * 4 + 0) * 32);
          float4 v1 = *(const float4*)(h0vL0 + (s * 4 + 1) * 32);
          float4 v2 = *(const float4*)(h0vL0 + (s * 4 + 2) * 32);
          float4 v3 = *(const float4*)(h0vL0 + (s * 4 + 3) * 32);
          #pragma unroll
          for (int g = 0; g < 4; g++) {
            float4 w = *(const float4*)&wAh[dim][g][c][s * 4];
            float* a = acc + g * 4;
            a[0]=fmaf(w.x,v0.x,a[0]); a[0]=fmaf(w.y,v1.x,a[0]); a[0]=fmaf(w.z,v2.x,a[0]); a[0]=fmaf(w.w,v3.x,a[0]);
            a[1]=fmaf(w.x,v0.y,a[1]); a[1]=fmaf(w.y,v1.y,a[1]); a[1]=fmaf(w.z,v2.y,a[1]); a[1]=fmaf(w.w,v3.y,a[1]);
            a[2]=fmaf(w.x,v0.z,a[2]); a[2]=fmaf(w.y,v1.z,a[2]); a[2]=fmaf(w.z,v2.z,a[2]); a[2]=fmaf(w.w,v3.z,a[2]);
            a[3]=fmaf(w.x,v0.w,a[3]); a[3]=fmaf(w.y,v1.w,a[3]); a[3]=fmaf(w.z,v2.w,a[3]); a[3]=fmaf(w.w,v3.w,a[3]);
          }
        }
      }
      {
        const float* zt = zqT + (size_t)t * 2048 + b0;
        float4 u0 = *(const float4*)(zt + (c * 2 + 0) * 32);
        float4 u1 = *(const float4*)(zt + (c * 2 + 1) * 32);
        #pragma unroll
        for (int g = 0; g < 4; g++) {
          float wx = wAz[dim][g][c * 2 + 0], wy = wAz[dim][g][c * 2 + 1];
          float* a = acc + g * 4;
          a[0]=fmaf(wx,u0.x,a[0]); a[0]=fmaf(wy,u1.x,a[0]);
          a[1]=fmaf(wx,u0.y,a[1]); a[1]=fmaf(wy,u1.y,a[1]);
          a[2]=fmaf(wx,u0.z,a[2]); a[2]=fmaf(wy,u1.z,a[2]);
          a[3]=fmaf(wx,u0.w,a[3]); a[3]=fmaf(wy,u1.w,a[3]);
        }
      }
      // reduce: same tree order m = 1,2,4,8,16 (bit-identical)
      #pragma unroll
      for (int r = 0; r < 16; r++) acc[r] += dpp_xor1(acc[r]);
      #pragma unroll
      for (int r = 0; r < 16; r++) acc[r] += dpp_xor2(acc[r]);
      #pragma unroll
      for (int r = 0; r < 16; r++) acc[r] += swz_xor4(acc[r]);
      #pragma unroll
      for (int r = 0; r < 16; r++) acc[r] += dpp_xor8(acc[r]);
      #pragma unroll
      for (int r = 0; r < 16; r++) acc[r] += swz_xor16(acc[r]);
      if (c < 4) {
        int b = b0 + c;
        float gi = sigmoidf_(acc[0 * 4 + c] + bA[0]);
        float gf = sigmoidf_(acc[1 * 4 + c] + bA[1]);
        float gg = tanhf    (acc[2 * 4 + c] + bA[2]);
        float go = sigmoidf_(acc[3 * 4 + c] + bA[3]);
        float cn = fmaf(gf, creg0, gi * gg);
        creg0 = cn;
        store_f32_wt(h0T + ((t + 1) & 1) * 16384 + j * 32 + b, go * tanhf(cn));
      }
    }

    // ---- L1 step t-1: h1 (global, hoisted cluster) for c<16; h0 (LDS) for c>=16 ----
    if (t >= 1 && t <= nTP) {
      const float* h1p = h1T + ((t - 1) & 1) * 16384;
      float4 vbuf[32];
      if (c < 16) {
        const float* vg = h1p + c * 32 * 32 + b0;
        #pragma unroll
        for (int k = 0; k < 32; k++) vbuf[k] = *(const float4*)(vg + k * 32);
      } else {
        #pragma unroll
        for (int k = 0; k < 16; k++) vbuf[k] = *(const float4*)(h0vA + k * 32);
        #pragma unroll
        for (int k = 0; k < 16; k++) vbuf[16 + k] = *(const float4*)(h0vB + k * 32);
      }
      float acc[16];
      #pragma unroll
      for (int r = 0; r < 16; r++) acc[r] = 0.f;
      #pragma unroll
      for (int s = 0; s < 8; s++) {
        float4 v0 = vbuf[s * 4 + 0];
        float4 v1 = vbuf[s * 4 + 1];
        float4 v2 = vbuf[s * 4 + 2];
        float4 v3 = vbuf[s * 4 + 3];
        #pragma unroll
        for (int g = 0; g < 4; g++) {
          float4 w = *(const float4*)&wB[dim][g][c][s * 4];
          float* a = acc + g * 4;
          a[0]=fmaf(w.x,v0.x,a[0]); a[0]=fmaf(w.y,v1.x,a[0]); a[0]=fmaf(w.z,v2.x,a[0]); a[0]=fmaf(w.w,v3.x,a[0]);
          a[1]=fmaf(w.x,v0.y,a[1]); a[1]=fmaf(w.y,v1.y,a[1]); a[1]=fmaf(w.z,v2.y,a[1]); a[1]=fmaf(w.w,v3.y,a[1]);
          a[2]=fmaf(w.x,v0.z,a[2]); a[2]=fmaf(w.y,v1.z,a[2]); a[2]=fmaf(w.z,v2.z,a[2]); a[2]=fmaf(w.w,v3.z,a[2]);
          a[3]=fmaf(w.x,v0.w,a[3]); a[3]=fmaf(w.y,v1.w,a[3]); a[3]=fmaf(w.z,v2.w,a[3]); a[3]=fmaf(w.w,v3.w,a[3]);
        }
      }
      #pragma unroll
      for (int r = 0; r < 16; r++) acc[r] += dpp_xor1(acc[r]);
      #pragma unroll
      for (int r = 0; r < 16; r++) acc[r] += dpp_xor2(acc[r]);
      #pragma unroll
      for (int r = 0; r < 16; r++) acc[r] += swz_xor4(acc[r]);
      #pragma unroll
      for (int r = 0; r < 16; r++) acc[r] += dpp_xor8(acc[r]);
      #pragma unroll
      for (int r = 0; r < 16; r++) acc[r] += swz_xor16(acc[r]);
      if (c < 4) {
        int b = b0 + c;
        float gi = sigmoidf_(acc[0 * 4 + c] + bB4[0]);
        float gf = sigmoidf_(acc[1 * 4 + c] + bB4[1]);
        float gg = tanhf    (acc[2 * 4 + c] + bB4[2]);
        float go = sigmoidf_(acc[3 * 4 + c] + bB4[3]);
        float cn = fmaf(gf, creg1, gi * gg);
        creg1 = cn;
        store_f32_wt(h1T + (t & 1) * 16384 + j * 32 + b, go * tanhf(cn));
      }
    }

    // drain this wave's loads and write-through stores, then block-wide rendezvous
    asm volatile("s_waitcnt vmcnt(0)" ::: "memory");
    __syncthreads();

    // ---- arrival flag (all waves drained at this point) ----
    if (t <= nTP && tid == 0) store_u32_wt(flags + blk, (unsigned)(t + 1));

    // ---- head for step t-2 on wave 1, overlapping the barrier wait ----
    // STANDALONE guard: must also run at t == nTP+1 (emits output step 1023).
    if (t >= 2 && blk < 96 && tid >= 64 && tid < 80) {
      int q = (tid >> 3) & 1, l = tid & 7;
      int p = blk * 2 + q;
      int b = p & 31;
      const float* h1s = h1T + ((t - 1) & 1) * 16384;   // h1 step t-2 (covered by barrier t-1)
      float a = 0.f;
      #pragma unroll 8
      for (int m = 0; m < 64; m++) {
        int i = l * 64 + m;
        a = fmaf(wHd[q][i], h1s[i * 32 + b], a);
      }
      a += __shfl_down(a, 4, 8);
      a += __shfl_down(a, 2, 8);
      a += __shfl_down(a, 1, 8);
      if (l == 0) out[((size_t)b * nTP + (t - 2)) * 6 + (p >> 5)] = a + bHd[q];
    }

    // ---- master/release barrier: block 0 detects (64 pollers total), then
    //      broadcasts to 256 PRIVATE release lines; each block polls its own ----
    if (t <= nTP) {
      unsigned tgt = (unsigned)(t + 1);
      if (blk == 0) {
        if (tid < 64) {
          const u32x4* fp = (const u32x4*)flags + tid;
          for (;;) {
            u32x4 f;
            asm volatile("global_load_dwordx4 %0, %1, off sc0 sc1\n\ts_waitcnt vmcnt(0)"
                         : "=&v"(f) : "v"(fp) : "memory");
            bool ok = (f.x >= tgt) && (f.y >= tgt) && (f.z >= tgt) && (f.w >= tgt);
            if (__all(ok)) break;
            __builtin_amdgcn_s_sleep(1);
          }
          // release broadcast: each lane owns 4 private 64B lines
          unsigned* rp = rel + tid * 64;
          #pragma unroll
          for (int q = 0; q < 4; q++) store_u32_wt(rp + q * 16, tgt);
          __builtin_amdgcn_fence(__ATOMIC_ACQUIRE, "agent");  // buffer_inv
        }
      } else {
        if (tid == 0) {
          const unsigned* rp = rel + blk * 16;   // this block's private release line
          while (load_u32_wt(rp) < tgt) __builtin_amdgcn_s_sleep(1);
        }
        if (tid < 64) __builtin_amdgcn_fence(__ATOMIC_ACQUIRE, "agent");  // buffer_inv
      }
      __syncthreads();
    }
  }
}

// ---------------- launch ----------------

extern "C" void kernel_launch(void* const* d_in, const int* in_sizes, int n_in,
                              void* d_out, int out_size, void* d_ws, size_t ws_size,
                              hipStream_t stream) {
  (void)in_sizes; (void)n_in; (void)out_size; (void)ws_size;
  const float* x    = (const float*)d_in[0];
  const float* w1   = (const float*)d_in[1];
  const float* b1   = (const float*)d_in[2];
  const float* w2   = (const float*)d_in[3];
  const float* b2   = (const float*)d_in[4];
  const float* w3   = (const float*)d_in[5];
  const float* b3   = (const float*)d_in[6];
  const float* cb   = (const float*)d_in[7];
  const float* wih0 = (const float*)d_in[8];
  const float* whh0 = (const float*)d_in[9];
  const float* bl0  = (const float*)d_in[10];
  const float* wih1 = (const float*)d_in[11];
  const float* whh1 = (const float*)d_in[12];
  const float* bl1  = (const float*)d_in[13];
  const float* wout = (const float*)d_in[14];
  const float* bout = (const float*)d_in[15];
  float* out = (float*)d_out;

  float* ws  = (float*)d_ws;
  // region reuse: st+flags overlaps sig (dead after conv1); zqT overlaps h1c (dead after conv2)
  float* sig = ws;                 // 131072 floats (later: h0T/h1T 65536 + flags/rel)
  float* h1c = sig + 131072;       // 4194304  [32][64][2048] (later: zqT, 2097152)
  float* h2c = h1c + 4194304;      // 2097152  [32][64][1024]
  float* ze  = h2c + 2097152;      // 2097152  [32][64][1024]
  float* zq  = ze  + 2097152;      // 2097152  [32*1024][64]
  float* cbn = zq  + 2097152;      // 256
  float* stp = ws;                 // h0T[2][512][32], h1T[2][512][32], flags[1024], rel[4096]
  float* zqT = h1c;                // 2097152  [1024][64][32]

  k_mean <<<32768, 256, 0, stream>>>(x, sig);
  k_conv1<<<16384, 256, 0, stream>>>(sig, w1, b1, h1c);
  hipMemsetAsync(stp, 0, (65536 + 1024 + 4096) * sizeof(float), stream);  // state + flags + rel
  k_conv2<<<8192, 256, 0, stream>>>(h1c, w2, b2, h2c);
  k_conv3<<<8192, 256, 0, stream>>>(h2c, w3, b3, ze);
  k_cbnorm<<<1, 256, 0, stream>>>(cb, cbn);
  k_vq   <<<128, 256, 0, stream>>>(ze, cb, cbn, zq);
  k_zqt  <<<1024, 256, 0, stream>>>(zq, zqT);   // h1c dead now; write zqT over it

  void* kargs[] = { (void*)&zqT, (void*)&wih0, (void*)&whh0, (void*)&bl0,
                    (void*)&wih1, (void*)&whh1, (void*)&bl1,
                    (void*)&wout, (void*)&bout, (void*)&stp, (void*)&out };
  hipLaunchCooperativeKernel((void*)k_lstm, dim3(256), dim3(512), kargs, 0, stream);
}